// Round 15
// baseline (260.049 us; speedup 1.0000x reference)
//
#include <hip/hip_runtime.h>
#include <hip/hip_bf16.h>

typedef __bf16 bf16x8 __attribute__((ext_vector_type(8)));
typedef float f32x4 __attribute__((ext_vector_type(4)));
typedef unsigned short ushort_t;

#define S_LEN 4096
#define D_DIM 512
#define NBATCH 4
#define NROW (NBATCH * S_LEN)
#define QKSTR 1024   // fused QK buffer row stride (Q cols 0-511, K cols 512-1023)

static __device__ __forceinline__ ushort_t f2bf(float f) {
    __hip_bfloat16 h = __float2bfloat16(f);
    return __builtin_bit_cast(ushort_t, h);
}

typedef unsigned int __attribute__((address_space(1))) as1_uint;
typedef unsigned int __attribute__((address_space(3))) as3_uint;

// async 16B/lane global->LDS (wave-uniform LDS base + lane*16; global src per-lane)
static __device__ __forceinline__ void gll16(const ushort_t* src, ushort_t* dst) {
    __builtin_amdgcn_global_load_lds((const as1_uint*)(const void*)src,
                                     (as3_uint*)(void*)dst, 16, 0, 0);
}

// ---------------- fp32 -> bf16 convert (with optional scale) ----------------
__global__ void cvt_bf16_kernel(const float* __restrict__ src, ushort_t* __restrict__ dst,
                                int n4, float scale) {
    int i = blockIdx.x * blockDim.x + threadIdx.x;
    if (i >= n4) return;
    float4 v = reinterpret_cast<const float4*>(src)[i];
    ushort4 o;
    o.x = f2bf(v.x * scale);
    o.y = f2bf(v.y * scale);
    o.z = f2bf(v.z * scale);
    o.w = f2bf(v.w * scale);
    reinterpret_cast<ushort4*>(dst)[i] = o;
}

// ---------------- bf16 GEMM (m97-style): C[M][N] = A[M][K] * Bt[N][K]^T ----------------
__global__ __launch_bounds__(256) void gemm_bt(const ushort_t* __restrict__ A,
                                               const ushort_t* __restrict__ Bt,
                                               ushort_t* __restrict__ C,
                                               int M, int N, int K) {
    __shared__ ushort_t As[128 * 32];   // 8 KB, linear (gll16 dest)
    __shared__ ushort_t Bs[128 * 32];
    int tid = threadIdx.x;
    int w = tid >> 6, lane = tid & 63, c = lane & 15, g = lane >> 4;
    int m0 = blockIdx.x * 128, n0 = blockIdx.y * 128;
    int wm = (w >> 1) * 64, wn = (w & 1) * 64;

    f32x4 acc[4][4];
#pragma unroll
    for (int mi = 0; mi < 4; mi++)
#pragma unroll
        for (int ni = 0; ni < 4; ni++) acc[mi][ni] = (f32x4){0.f, 0.f, 0.f, 0.f};

    for (int k0 = 0; k0 < K; k0 += 32) {
        __syncthreads();
#pragma unroll
        for (int rr = 0; rr < 2; rr++) {
            int cl = rr * 256 + tid;
            int row = cl >> 2, slot = cl & 3;
            int ch = slot ^ ((row >> 1) & 3);
            gll16(A + (size_t)(m0 + row) * K + k0 + ch * 8, &As[cl * 8]);
            gll16(Bt + (size_t)(n0 + row) * K + k0 + ch * 8, &Bs[cl * 8]);
        }
        __syncthreads();   // gll16s drained

        bf16x8 af[4], bfr[4];
#pragma unroll
        for (int i2 = 0; i2 < 4; i2++) {
            int row = wm + i2 * 16 + c;
            af[i2] = *(const bf16x8*)(&As[row * 32 + (g ^ ((row >> 1) & 3)) * 8]);
        }
#pragma unroll
        for (int i2 = 0; i2 < 4; i2++) {
            int row = wn + i2 * 16 + c;
            bfr[i2] = *(const bf16x8*)(&Bs[row * 32 + (g ^ ((row >> 1) & 3)) * 8]);
        }
#pragma unroll
        for (int mi = 0; mi < 4; mi++)
#pragma unroll
            for (int ni = 0; ni < 4; ni++)
                acc[mi][ni] = __builtin_amdgcn_mfma_f32_16x16x32_bf16(af[mi], bfr[ni],
                                                                      acc[mi][ni], 0, 0, 0);
    }

#pragma unroll
    for (int mi = 0; mi < 4; mi++)
#pragma unroll
        for (int ni = 0; ni < 4; ni++)
#pragma unroll
            for (int j = 0; j < 4; j++)
                C[(size_t)(m0 + wm + mi * 16 + g * 4 + j) * N + n0 + wn + ni * 16 + c] =
                    f2bf(acc[mi][ni][j]);
}

// ------------- flash attention partials: pipelined QK->PV, ONE barrier per tile -------------
// R11 skeleton (kv-half-split QK, deferred correction) with PV lagging QK by one tile.
// Slot s: barrier; bookkeep tile s-1 (merge mh halves -> m/l chains); issue K(s+1)->Ks[pi^1],
// V(s)->Vs[pi]; QK(s) from Ks[pi] -> P(s)->Ps[pi], mh(s)->mhP[pi]; PV(s-1) from Ps[pi^1]/
// Vs[pi^1]/mhP[pi^1]. Every DMA gets a full slot of latency; 1 barrier/slot.
#define KVB 32
#define PPAD 40
#define PSZ (4 * 16 * PPAD)

__global__ __launch_bounds__(512, 2) void attn_part_kernel(const ushort_t* __restrict__ QK,
                                                           const ushort_t* __restrict__ Vt,
                                                           float* __restrict__ out0,
                                                           float* __restrict__ out1,
                                                           float* __restrict__ ml) {
    __shared__ ushort_t Ks[2][KVB][512];      // 64 KB (chunk-swizzled: pos = ch ^ (row&7))
    __shared__ ushort_t Vs[2][512][KVB];      // 64 KB (chunk-swizzled)
    __shared__ ushort_t Ps[2][PSZ];           // 10 KB, parity-buffered P
    __shared__ float mhP[2][2][64];           // [parity][half][row]
    __shared__ float lhalf[2 * 64];

    const int gid = blockIdx.x;
    const int b = gid & 3;
    const int h = (gid >> 2) & 1;
    const int p = gid >> 3;            // 0..31
    const int tid = threadIdx.x;
    const int w = tid >> 6, lane = tid & 63, c = lane & 15, g = lane >> 4;
    const int r = w & 3, d = w >> 2;   // q row-group, kv-half / D-half

    const ushort_t* Q  = QK;           // cols 0-511 of fused buffer
    const ushort_t* Kp = QK + 512;     // cols 512-1023

    const int sbase = b * S_LEN;
    float* po = h ? out1 : out0;
    const int hc = (c ^ (c >> 2)) & 3;            // V-read swizzle hash
    const int vrr = lane >> 2, vpc = lane & 3;    // V-stage row/chunk within 16-row group
    const int vhh = (vrr ^ (vrr >> 2)) & 3;       // V-stage swizzle hash

    for (int phase = 0; phase < 2; ++phase) {
        const int jblk = phase ? (63 - p) : p;
        const int qbase = jblk * 64;
        const int NT = jblk + 1;       // slots 0..NT; QK on 0..jblk, PV on 1..NT

        // Q fragments (1/sqrt(512) folded into W_q)
        bf16x8 qf[16];
        {
            const ushort_t* qrow = Q + (size_t)(sbase + qbase + r * 16 + c) * QKSTR;
#pragma unroll
            for (int kk = 0; kk < 16; kk++)
                qf[kk] = *(const bf16x8*)(qrow + kk * 32 + g * 8);
        }

        f32x4 o[16];
#pragma unroll
        for (int t = 0; t < 16; t++) o[t] = (f32x4){0.f, 0.f, 0.f, 0.f};
        float m_r = -1e30f, l_r = 0.f;        // chain for row rho = r*16+c (own-half l)
        float rs_sv = 0.f, mloc_sv = -1e30f;  // QK(s) products consumed at slot s+1

        // ---- prologue: issue K(0) into Ks[0] ----
        {
            const ushort_t* kg = Kp + (size_t)(sbase + h * KVB) * QKSTR;
#pragma unroll
            for (int ii = 0; ii < 4; ii++) {
                int row = w * 4 + ii;
                gll16(kg + (size_t)row * QKSTR + ((lane ^ (row & 7)) * 8), &Ks[0][row][0]);
            }
        }

        for (int s = 0; s <= NT; ++s) {
            const int pi = s & 1;
            __syncthreads();   // drains K(s), V(s-1); P(s-1)/mh(s-1) visible

            // ---- bookkeeping for tile s-1: merge halves, advance m/l chains ----
            float mh0 = -1e30f, mh1 = -1e30f, alpha = 1.f;
            if (s > 0) {
                mh0 = mhP[pi ^ 1][0][r * 16 + c];
                mh1 = mhP[pi ^ 1][1][r * 16 + c];
                float mnew = fmaxf(mh0, mh1);
                alpha = __expf(m_r - mnew);   // == 1.0f exactly when max unchanged
                l_r = l_r * alpha + rs_sv * __expf(mloc_sv - mnew);
                m_r = mnew;                   // M(s-1) for the rest of this slot
            }

            // ---- issue K(s+1) and V(s) (drain at next slot's barrier) ----
            if (s + 1 <= jblk) {
                const int kv0n = (h + 2 * (s + 1)) * KVB;
                const ushort_t* kg = Kp + (size_t)(sbase + kv0n) * QKSTR;
#pragma unroll
                for (int ii = 0; ii < 4; ii++) {
                    int row = w * 4 + ii;
                    gll16(kg + (size_t)row * QKSTR + ((lane ^ (row & 7)) * 8),
                          &Ks[pi ^ 1][row][0]);
                }
            }
            if (s <= jblk) {
                const int kv0v = (h + 2 * s) * KVB;
#pragma unroll
                for (int ii = 0; ii < 4; ii++) {
                    int grp = w * 4 + ii;
                    gll16(Vt + (size_t)(grp * 16 + vrr) * NROW + sbase + kv0v +
                              ((vpc ^ vhh) * 8),
                          &Vs[pi][grp * 16][0]);
                }
            }

            // ---- QK(s): S^T[16 kv of half d][16 q of r] ----
            if (s <= jblk) {
                const int kv0 = (h + 2 * s) * KVB;
                f32x4 s4 = (f32x4){0.f, 0.f, 0.f, 0.f};
#pragma unroll
                for (int kk = 0; kk < 16; kk++) {
                    bf16x8 kf = *(const bf16x8*)(
                        &Ks[pi][d * 16 + c][((4 * kk + g) ^ (c & 7)) * 8]);
                    s4 = __builtin_amdgcn_mfma_f32_16x16x32_bf16(kf, qf[kk], s4, 0, 0, 0);
                }
                if (s == jblk) {
                    int qrow = qbase + r * 16 + c;
#pragma unroll
                    for (int jj = 0; jj < 4; jj++) {
                        int kvcol = kv0 + d * 16 + g * 4 + jj;
                        if (kvcol > qrow) s4[jj] = -1e38f;
                    }
                }
                float pm = fmaxf(fmaxf(s4[0], s4[1]), fmaxf(s4[2], s4[3]));
                pm = fmaxf(pm, __shfl_xor(pm, 16, 64));
                pm = fmaxf(pm, __shfl_xor(pm, 32, 64));
                float m_loc = fmaxf(m_r, pm);   // m_r == M(s-1)
                float pv[4], rs = 0.f;
#pragma unroll
                for (int jj = 0; jj < 4; jj++) {
                    pv[jj] = __expf(s4[jj] - m_loc);
                    rs += pv[jj];
                }
                rs += __shfl_xor(rs, 16, 64);
                rs += __shfl_xor(rs, 32, 64);
                {
                    ushort4 u;
                    u.x = f2bf(pv[0]);
                    u.y = f2bf(pv[1]);
                    u.z = f2bf(pv[2]);
                    u.w = f2bf(pv[3]);
                    *(ushort4*)(&Ps[pi][(r * 16 + c) * PPAD + d * 16 + g * 4]) = u;
                }
                if (g == 0) mhP[pi][d][r * 16 + c] = m_loc;
                rs_sv = rs;
                mloc_sv = m_loc;
            }

            // ---- PV(s-1): O += corr(P(s-1)) * V(s-1), D-half d ----
            if (s > 0) {
                if (__any((int)(alpha != 1.f))) {
                    float aq[4];
#pragma unroll
                    for (int jj = 0; jj < 4; jj++)
                        aq[jj] = __shfl(alpha, (lane & 48) | (g * 4 + jj), 64);
#pragma unroll
                    for (int dt = 0; dt < 16; dt++)
#pragma unroll
                        for (int jj = 0; jj < 4; jj++) o[dt][jj] *= aq[jj];
                }
                float corr_pa = __expf(((g >> 1) ? mh1 : mh0) - m_r);  // m_r == M(s-1)
                bf16x8 pr = *(const bf16x8*)(
                    &Ps[pi ^ 1][(r * 16 + c) * PPAD + g * 8]);
                bf16x8 pa;
#pragma unroll
                for (int i2 = 0; i2 < 8; i2++)
                    pa[i2] = (__bf16)((float)pr[i2] * corr_pa);
#pragma unroll
                for (int dt = 0; dt < 16; dt++) {
                    bf16x8 vf = *(const bf16x8*)(
                        &Vs[pi ^ 1][d * 256 + dt * 16 + c][(g ^ hc) * 8]);
                    o[dt] = __builtin_amdgcn_mfma_f32_16x16x32_bf16(pa, vf, o[dt], 0, 0, 0);
                }
            }
        }

        // ---- epilogue: exchange per-half l, write raw partial + (m, l_tot) ----
        if (g == 0) lhalf[d * 64 + r * 16 + c] = l_r;
        __syncthreads();
        float l_tot = l_r + lhalf[(1 ^ d) * 64 + r * 16 + c];
#pragma unroll
        for (int dt = 0; dt < 16; dt++)
#pragma unroll
            for (int jj = 0; jj < 4; jj++)
                po[(size_t)(sbase + qbase + r * 16 + g * 4 + jj) * D_DIM +
                   d * 256 + dt * 16 + c] = o[dt][jj];
        if (d == 0 && g == 0) {
            int row = sbase + qbase + r * 16 + c;
            ml[((size_t)h * NROW + row) * 2 + 0] = m_r;
            ml[((size_t)h * NROW + row) * 2 + 1] = l_tot;
        }
        __syncthreads();   // mhP/lhalf/buffers safe for next phase
    }
}

// ---------------- merge the two h-split partials ----------------
__global__ __launch_bounds__(256) void attn_merge_kernel(float* __restrict__ out,
                                                         const float* __restrict__ part1,
                                                         const float* __restrict__ ml) {
    int i = blockIdx.x * blockDim.x + threadIdx.x;   // float4 index
    int row = i >> 7;                                 // 128 float4 per row
    float m0 = ml[(size_t)row * 2 + 0], l0 = ml[(size_t)row * 2 + 1];
    float m1 = ml[((size_t)NROW + row) * 2 + 0], l1 = ml[((size_t)NROW + row) * 2 + 1];
    float mm = fmaxf(m0, m1);
    float a0 = __expf(m0 - mm), a1 = __expf(m1 - mm);
    float inv = 1.f / (l0 * a0 + l1 * a1);
    float4 x0 = reinterpret_cast<float4*>(out)[i];
    float4 x1 = reinterpret_cast<const float4*>(part1)[i];
    float4 r;
    r.x = (x0.x * a0 + x1.x * a1) * inv;
    r.y = (x0.y * a0 + x1.y * a1) * inv;
    r.z = (x0.z * a0 + x1.z * a1) * inv;
    r.w = (x0.w * a0 + x1.w * a1) * inv;
    reinterpret_cast<float4*>(out)[i] = r;
}

// ---------------- host launch ----------------
extern "C" void kernel_launch(void* const* d_in, const int* in_sizes, int n_in,
                              void* d_out, int out_size, void* d_ws, size_t ws_size,
                              hipStream_t stream) {
    const float* X  = (const float*)d_in[0];
    const float* Wq = (const float*)d_in[1];
    const float* Wk = (const float*)d_in[2];
    const float* Wv = (const float*)d_in[3];
    float* out = (float*)d_out;

    const int M = NROW;             // 16384
    const int Kd = D_DIM;           // 512
    const size_t XBF_BYTES  = (size_t)M * Kd * 2;        // 16.8 MB
    const size_t W_BYTES    = (size_t)Kd * Kd * 2;       // 0.5 MB
    const size_t QK_BYTES   = (size_t)M * QKSTR * 2;     // 33.6 MB

    char* p = (char*)d_ws;
    ushort_t* Xbf  = (ushort_t*)p;             p += XBF_BYTES;
    ushort_t* Wqkb = (ushort_t*)p;             p += 2 * W_BYTES;   // [1024][512]
    ushort_t* Wvb  = (ushort_t*)p;             p += W_BYTES;
    ushort_t* QKb  = (ushort_t*)p;             p += QK_BYTES;      // [16384][1024]
    ushort_t* Vtb  = (ushort_t*)p;             p += XBF_BYTES;     // [512][16384]
    float*    part1 = (float*)p;               p += (size_t)M * Kd * 4;  // 32 MB
    float*    mlb   = (float*)p;               p += (size_t)2 * M * 2 * 4;

    const float qscale = 0.044194173824159216f;  // 1/sqrt(512)

    {
        int n4 = (M * Kd) / 4;
        cvt_bf16_kernel<<<(n4 + 255) / 256, 256, 0, stream>>>(X, Xbf, n4, 1.0f);
        int w4 = (Kd * Kd) / 4;
        cvt_bf16_kernel<<<(w4 + 255) / 256, 256, 0, stream>>>(Wq, Wqkb, w4, qscale);
        cvt_bf16_kernel<<<(w4 + 255) / 256, 256, 0, stream>>>(Wk, Wqkb + Kd * Kd, w4, 1.0f);
        cvt_bf16_kernel<<<(w4 + 255) / 256, 256, 0, stream>>>(Wv, Wvb, w4, 1.0f);
    }
    // fused [Q|K] projection: C[16384][1024] = X * [Wq;Wk]^T
    gemm_bt<<<dim3(M / 128, QKSTR / 128), 256, 0, stream>>>(Xbf, Wqkb, QKb, M, QKSTR, Kd);
    // V^T = Wv * X^T : C[512][16384]
    gemm_bt<<<dim3(Kd / 128, M / 128), 256, 0, stream>>>(Wvb, Xbf, Vtb, Kd, M, Kd);

    attn_part_kernel<<<256, 512, 0, stream>>>(QKb, Vtb, out, part1, mlb);
    attn_merge_kernel<<<(M * Kd / 4) / 256, 256, 0, stream>>>(out, part1, mlb);
}

// Round 16
// 241.698 us; speedup vs baseline: 1.0759x; 1.0759x over previous
//
#include <hip/hip_runtime.h>
#include <hip/hip_bf16.h>

typedef __bf16 bf16x8 __attribute__((ext_vector_type(8)));
typedef float f32x4 __attribute__((ext_vector_type(4)));
typedef unsigned short ushort_t;

#define S_LEN 4096
#define D_DIM 512
#define NBATCH 4
#define NROW (NBATCH * S_LEN)
#define QKSTR 1024   // fused QK buffer row stride (Q cols 0-511, K cols 512-1023)

static __device__ __forceinline__ ushort_t f2bf(float f) {
    __hip_bfloat16 h = __float2bfloat16(f);
    return __builtin_bit_cast(ushort_t, h);
}
static __device__ __forceinline__ float bf2f(ushort_t u) {
    unsigned int x = ((unsigned int)u) << 16;
    return __builtin_bit_cast(float, x);
}

typedef unsigned int __attribute__((address_space(1))) as1_uint;
typedef unsigned int __attribute__((address_space(3))) as3_uint;

// async 16B/lane global->LDS (wave-uniform LDS base + lane*16; global src per-lane)
static __device__ __forceinline__ void gll16(const ushort_t* src, ushort_t* dst) {
    __builtin_amdgcn_global_load_lds((const as1_uint*)(const void*)src,
                                     (as3_uint*)(void*)dst, 16, 0, 0);
}

// ---------------- fp32 -> bf16 convert (with optional scale) ----------------
__global__ void cvt_bf16_kernel(const float* __restrict__ src, ushort_t* __restrict__ dst,
                                int n4, float scale) {
    int i = blockIdx.x * blockDim.x + threadIdx.x;
    if (i >= n4) return;
    float4 v = reinterpret_cast<const float4*>(src)[i];
    ushort4 o;
    o.x = f2bf(v.x * scale);
    o.y = f2bf(v.y * scale);
    o.z = f2bf(v.z * scale);
    o.w = f2bf(v.w * scale);
    reinterpret_cast<ushort4*>(dst)[i] = o;
}

// ---------------- bf16 GEMM (m97-style): C[M][N] = A[M][K] * Bt[N][K]^T ----------------
__global__ __launch_bounds__(256) void gemm_bt(const ushort_t* __restrict__ A,
                                               const ushort_t* __restrict__ Bt,
                                               ushort_t* __restrict__ C,
                                               int M, int N, int K) {
    __shared__ ushort_t As[128 * 32];   // 8 KB, linear (gll16 dest)
    __shared__ ushort_t Bs[128 * 32];
    int tid = threadIdx.x;
    int w = tid >> 6, lane = tid & 63, c = lane & 15, g = lane >> 4;
    int m0 = blockIdx.x * 128, n0 = blockIdx.y * 128;
    int wm = (w >> 1) * 64, wn = (w & 1) * 64;

    f32x4 acc[4][4];
#pragma unroll
    for (int mi = 0; mi < 4; mi++)
#pragma unroll
        for (int ni = 0; ni < 4; ni++) acc[mi][ni] = (f32x4){0.f, 0.f, 0.f, 0.f};

    for (int k0 = 0; k0 < K; k0 += 32) {
        __syncthreads();
#pragma unroll
        for (int rr = 0; rr < 2; rr++) {
            int cl = rr * 256 + tid;
            int row = cl >> 2, slot = cl & 3;
            int ch = slot ^ ((row >> 1) & 3);
            gll16(A + (size_t)(m0 + row) * K + k0 + ch * 8, &As[cl * 8]);
            gll16(Bt + (size_t)(n0 + row) * K + k0 + ch * 8, &Bs[cl * 8]);
        }
        __syncthreads();   // gll16s drained

        bf16x8 af[4], bfr[4];
#pragma unroll
        for (int i2 = 0; i2 < 4; i2++) {
            int row = wm + i2 * 16 + c;
            af[i2] = *(const bf16x8*)(&As[row * 32 + (g ^ ((row >> 1) & 3)) * 8]);
        }
#pragma unroll
        for (int i2 = 0; i2 < 4; i2++) {
            int row = wn + i2 * 16 + c;
            bfr[i2] = *(const bf16x8*)(&Bs[row * 32 + (g ^ ((row >> 1) & 3)) * 8]);
        }
#pragma unroll
        for (int mi = 0; mi < 4; mi++)
#pragma unroll
            for (int ni = 0; ni < 4; ni++)
                acc[mi][ni] = __builtin_amdgcn_mfma_f32_16x16x32_bf16(af[mi], bfr[ni],
                                                                      acc[mi][ni], 0, 0, 0);
    }

#pragma unroll
    for (int mi = 0; mi < 4; mi++)
#pragma unroll
        for (int ni = 0; ni < 4; ni++)
#pragma unroll
            for (int j = 0; j < 4; j++)
                C[(size_t)(m0 + wm + mi * 16 + g * 4 + j) * N + n0 + wn + ni * 16 + c] =
                    f2bf(acc[mi][ni][j]);
}

// ------------- flash attention partials: kv-half-split QK with deferred correction -------------
// (R11/R14 skeleton — best measured. R16 adds: bf16 partials, s_setprio around MFMA
// clusters, dual QK accumulator chains.)
#define KVB 32
#define PPAD 40

__global__ __launch_bounds__(512, 2) void attn_part_kernel(const ushort_t* __restrict__ QK,
                                                           const ushort_t* __restrict__ Vt,
                                                           ushort_t* __restrict__ part0,
                                                           ushort_t* __restrict__ part1,
                                                           float* __restrict__ ml) {
    __shared__ ushort_t Ks[2][KVB][512];      // 64 KB (chunk-swizzled: pos = ch ^ (row&7))
    __shared__ ushort_t Vs[2][512][KVB];      // 64 KB (chunk-swizzled)
    __shared__ ushort_t Ps[4 * 16 * PPAD];    // 5 KB, per-r-group shared
    __shared__ float mhalf[2 * 64];
    __shared__ float lhalf[2 * 64];

    const int gid = blockIdx.x;
    const int b = gid & 3;
    const int h = (gid >> 2) & 1;
    const int p = gid >> 3;            // 0..31
    const int tid = threadIdx.x;
    const int w = tid >> 6, lane = tid & 63, c = lane & 15, g = lane >> 4;
    const int r = w & 3, d = w >> 2;   // q row-group, kv-half / D-half

    const ushort_t* Q  = QK;           // cols 0-511 of fused buffer
    const ushort_t* Kp = QK + 512;     // cols 512-1023

    const int sbase = b * S_LEN;
    ushort_t* pw = Ps + r * 16 * PPAD;
    ushort_t* po = h ? part1 : part0;
    const int hc = (c ^ (c >> 2)) & 3;            // V-read swizzle hash
    const int vrr = lane >> 2, vpc = lane & 3;    // V-stage row/chunk within 16-row group
    const int vhh = (vrr ^ (vrr >> 2)) & 3;       // V-stage swizzle hash

    for (int phase = 0; phase < 2; ++phase) {
        const int jblk = phase ? (63 - p) : p;
        const int qbase = jblk * 64;

        // Q fragments (1/sqrt(512) folded into W_q); d-pair waves load the same 16 rows.
        bf16x8 qf[16];
        {
            const ushort_t* qrow = Q + (size_t)(sbase + qbase + r * 16 + c) * QKSTR;
#pragma unroll
            for (int kk = 0; kk < 16; kk++)
                qf[kk] = *(const bf16x8*)(qrow + kk * 32 + g * 8);
        }

        f32x4 o[16];
#pragma unroll
        for (int t = 0; t < 16; t++) o[t] = (f32x4){0.f, 0.f, 0.f, 0.f};
        float m_r = -1e30f, l_r = 0.f;   // per-lane chain: q-row = r*16 + c (own kv-half l)

        // ---- prologue: stage K[0] + V[0] into buf 0 ----
        {
            const int kv0 = h * KVB;
            const ushort_t* kg = Kp + (size_t)(sbase + kv0) * QKSTR;
#pragma unroll
            for (int ii = 0; ii < 4; ii++) {
                int row = w * 4 + ii;
                gll16(kg + (size_t)row * QKSTR + ((lane ^ (row & 7)) * 8), &Ks[0][row][0]);
            }
#pragma unroll
            for (int ii = 0; ii < 4; ii++) {
                int grp = w * 4 + ii;
                gll16(Vt + (size_t)(grp * 16 + vrr) * NROW + sbase + kv0 + ((vpc ^ vhh) * 8),
                      &Vs[0][grp * 16][0]);
            }
        }
        __syncthreads();   // buf0 staged (barrier drains vmcnt)

        for (int s = 0; s <= jblk; ++s) {
            const int cur = s & 1;
            const int kv0 = (h + 2 * s) * KVB;

            // ---- issue K-stage of stream tile s+1 (drains at barrier A, overlaps QK) ----
            if (s < jblk) {
                const int kv0n = (h + 2 * (s + 1)) * KVB;
                const ushort_t* kg = Kp + (size_t)(sbase + kv0n) * QKSTR;
#pragma unroll
                for (int ii = 0; ii < 4; ii++) {
                    int row = w * 4 + ii;
                    gll16(kg + (size_t)row * QKSTR + ((lane ^ (row & 7)) * 8),
                          &Ks[cur ^ 1][row][0]);
                }
            }

            // ---- QK^T : S^T[16 kv of half d][16 q of r], dual accumulator chains ----
            f32x4 s4 = (f32x4){0.f, 0.f, 0.f, 0.f};
            f32x4 s4b = (f32x4){0.f, 0.f, 0.f, 0.f};
            __builtin_amdgcn_s_setprio(1);
#pragma unroll
            for (int kk = 0; kk < 16; kk += 2) {
                bf16x8 kf0 = *(const bf16x8*)(
                    &Ks[cur][d * 16 + c][((4 * kk + g) ^ (c & 7)) * 8]);
                s4 = __builtin_amdgcn_mfma_f32_16x16x32_bf16(kf0, qf[kk], s4, 0, 0, 0);
                bf16x8 kf1 = *(const bf16x8*)(
                    &Ks[cur][d * 16 + c][((4 * (kk + 1) + g) ^ (c & 7)) * 8]);
                s4b = __builtin_amdgcn_mfma_f32_16x16x32_bf16(kf1, qf[kk + 1], s4b, 0, 0, 0);
            }
            __builtin_amdgcn_s_setprio(0);
            s4 = s4 + s4b;
            // s4[jj] = S[kv0 + d*16 + g*4 + jj][q = r*16 + c]

            // ---- causal mask (last stream tile touches the diagonal) ----
            if (s == jblk) {
                int qrow = qbase + r * 16 + c;
#pragma unroll
                for (int jj = 0; jj < 4; jj++) {
                    int kvcol = kv0 + d * 16 + g * 4 + jj;
                    if (kvcol > qrow) s4[jj] = -1e38f;
                }
            }

            // ---- local (half) softmax with m_loc; P = exp(s - m_loc) ----
            float pm = fmaxf(fmaxf(s4[0], s4[1]), fmaxf(s4[2], s4[3]));
            pm = fmaxf(pm, __shfl_xor(pm, 16, 64));
            pm = fmaxf(pm, __shfl_xor(pm, 32, 64));
            float m_loc = fmaxf(m_r, pm);
            float pv[4], rs = 0.f;
#pragma unroll
            for (int jj = 0; jj < 4; jj++) {
                pv[jj] = __expf(s4[jj] - m_loc);
                rs += pv[jj];
            }
            rs += __shfl_xor(rs, 16, 64);
            rs += __shfl_xor(rs, 32, 64);
            {
                ushort4 u;
                u.x = f2bf(pv[0]);
                u.y = f2bf(pv[1]);
                u.z = f2bf(pv[2]);
                u.w = f2bf(pv[3]);
                *(ushort4*)(&pw[c * PPAD + d * 16 + g * 4]) = u;
            }
            if (g == 0) mhalf[d * 64 + r * 16 + c] = m_loc;
            __syncthreads();   // A: P + mhalf visible; K-stage landed

            // ---- issue V-stage of stream tile s+1 (drains at barrier B, overlaps PV) ----
            if (s < jblk) {
                const int kv0n = (h + 2 * (s + 1)) * KVB;
#pragma unroll
                for (int ii = 0; ii < 4; ii++) {
                    int grp = w * 4 + ii;
                    gll16(Vt + (size_t)(grp * 16 + vrr) * NROW + sbase + kv0n +
                              ((vpc ^ vhh) * 8),
                          &Vs[cur ^ 1][grp * 16][0]);
                }
            }

            // ---- combine halves: mn, alpha, per-half corrections ----
            float mh0 = mhalf[r * 16 + c], mh1 = mhalf[64 + r * 16 + c];
            float mn = fmaxf(mh0, mh1);           // both already >= m_r
            float alpha = __expf(m_r - mn);       // == 1.0f exactly when max unchanged
            float corr_own = __expf((d ? mh1 : mh0) - mn);
            l_r = l_r * alpha + rs * corr_own;
            m_r = mn;

            // ---- rescale O (wave-uniform skip when all alphas == 1) ----
            if (__any((int)(alpha != 1.f))) {
                float aq[4];
#pragma unroll
                for (int jj = 0; jj < 4; jj++)
                    aq[jj] = __shfl(alpha, (lane & 48) | (g * 4 + jj), 64);
#pragma unroll
                for (int dt = 0; dt < 16; dt++)
#pragma unroll
                    for (int jj = 0; jj < 4; jj++) o[dt][jj] *= aq[jj];
            }

            // ---- pa read + per-lane half-correction (pa slice: g<2 -> half0, g>=2 -> half1) ----
            float corr_pa = __expf(((g >> 1) ? mh1 : mh0) - mn);
            bf16x8 pr = *(const bf16x8*)(&pw[c * PPAD + g * 8]);
            bf16x8 pa;
#pragma unroll
            for (int i2 = 0; i2 < 8; i2++)
                pa[i2] = (__bf16)((float)pr[i2] * corr_pa);

            // ---- PV : O[16 rows][256 cols (D-half d)] += P[16x32] * V[32x256] ----
            __builtin_amdgcn_s_setprio(1);
#pragma unroll
            for (int dt = 0; dt < 16; dt++) {
                bf16x8 vf = *(const bf16x8*)(&Vs[cur][d * 256 + dt * 16 + c][(g ^ hc) * 8]);
                o[dt] = __builtin_amdgcn_mfma_f32_16x16x32_bf16(pa, vf, o[dt], 0, 0, 0);
            }
            __builtin_amdgcn_s_setprio(0);

            __syncthreads();   // B: V-stage landed; buf[cur] + P reads done
        }

        // ---- epilogue: exchange per-half l, write bf16 raw partial + (m, l_tot) ----
        if (g == 0) lhalf[d * 64 + r * 16 + c] = l_r;
        __syncthreads();
        float l_tot = l_r + lhalf[(1 ^ d) * 64 + r * 16 + c];
#pragma unroll
        for (int dt = 0; dt < 16; dt++)
#pragma unroll
            for (int jj = 0; jj < 4; jj++)
                po[(size_t)(sbase + qbase + r * 16 + g * 4 + jj) * D_DIM +
                   d * 256 + dt * 16 + c] = f2bf(o[dt][jj]);
        if (d == 0 && g == 0) {
            int row = sbase + qbase + r * 16 + c;
            ml[((size_t)h * NROW + row) * 2 + 0] = m_r;
            ml[((size_t)h * NROW + row) * 2 + 1] = l_tot;
        }
        __syncthreads();   // mhalf/lhalf/buffers safe for next phase
    }
}

// ---------------- merge the two h-split bf16 partials -> f32 out ----------------
__global__ __launch_bounds__(256) void attn_merge_kernel(float* __restrict__ out,
                                                         const ushort_t* __restrict__ part0,
                                                         const ushort_t* __restrict__ part1,
                                                         const float* __restrict__ ml) {
    int i = blockIdx.x * blockDim.x + threadIdx.x;   // 4-elem group index
    int row = i >> 7;                                 // 128 groups per row
    float m0 = ml[(size_t)row * 2 + 0], l0 = ml[(size_t)row * 2 + 1];
    float m1 = ml[((size_t)NROW + row) * 2 + 0], l1 = ml[((size_t)NROW + row) * 2 + 1];
    float mm = fmaxf(m0, m1);
    float a0 = __expf(m0 - mm), a1 = __expf(m1 - mm);
    float inv = 1.f / (l0 * a0 + l1 * a1);
    ushort4 u0 = reinterpret_cast<const ushort4*>(part0)[i];
    ushort4 u1 = reinterpret_cast<const ushort4*>(part1)[i];
    float4 r;
    r.x = (bf2f(u0.x) * a0 + bf2f(u1.x) * a1) * inv;
    r.y = (bf2f(u0.y) * a0 + bf2f(u1.y) * a1) * inv;
    r.z = (bf2f(u0.z) * a0 + bf2f(u1.z) * a1) * inv;
    r.w = (bf2f(u0.w) * a0 + bf2f(u1.w) * a1) * inv;
    reinterpret_cast<float4*>(out)[i] = r;
}

// ---------------- host launch ----------------
extern "C" void kernel_launch(void* const* d_in, const int* in_sizes, int n_in,
                              void* d_out, int out_size, void* d_ws, size_t ws_size,
                              hipStream_t stream) {
    const float* X  = (const float*)d_in[0];
    const float* Wq = (const float*)d_in[1];
    const float* Wk = (const float*)d_in[2];
    const float* Wv = (const float*)d_in[3];
    float* out = (float*)d_out;

    const int M = NROW;             // 16384
    const int Kd = D_DIM;           // 512
    const size_t XBF_BYTES  = (size_t)M * Kd * 2;        // 16.8 MB
    const size_t W_BYTES    = (size_t)Kd * Kd * 2;       // 0.5 MB
    const size_t QK_BYTES   = (size_t)M * QKSTR * 2;     // 33.6 MB

    char* p = (char*)d_ws;
    ushort_t* Xbf   = (ushort_t*)p;            p += XBF_BYTES;
    ushort_t* Wqkb  = (ushort_t*)p;            p += 2 * W_BYTES;   // [1024][512]
    ushort_t* Wvb   = (ushort_t*)p;            p += W_BYTES;
    ushort_t* QKb   = (ushort_t*)p;            p += QK_BYTES;      // [16384][1024]
    ushort_t* Vtb   = (ushort_t*)p;            p += XBF_BYTES;     // [512][16384]
    ushort_t* part0 = (ushort_t*)p;            p += XBF_BYTES;     // bf16 partial h=0
    ushort_t* part1 = (ushort_t*)p;            p += XBF_BYTES;     // bf16 partial h=1
    float*    mlb   = (float*)p;               p += (size_t)2 * M * 2 * 4;

    const float qscale = 0.044194173824159216f;  // 1/sqrt(512)

    {
        int n4 = (M * Kd) / 4;
        cvt_bf16_kernel<<<(n4 + 255) / 256, 256, 0, stream>>>(X, Xbf, n4, 1.0f);
        int w4 = (Kd * Kd) / 4;
        cvt_bf16_kernel<<<(w4 + 255) / 256, 256, 0, stream>>>(Wq, Wqkb, w4, qscale);
        cvt_bf16_kernel<<<(w4 + 255) / 256, 256, 0, stream>>>(Wk, Wqkb + Kd * Kd, w4, 1.0f);
        cvt_bf16_kernel<<<(w4 + 255) / 256, 256, 0, stream>>>(Wv, Wvb, w4, 1.0f);
    }
    // fused [Q|K] projection: C[16384][1024] = X * [Wq;Wk]^T
    gemm_bt<<<dim3(M / 128, QKSTR / 128), 256, 0, stream>>>(Xbf, Wqkb, QKb, M, QKSTR, Kd);
    // V^T = Wv * X^T : C[512][16384]
    gemm_bt<<<dim3(Kd / 128, M / 128), 256, 0, stream>>>(Wvb, Xbf, Vtb, Kd, M, Kd);

    attn_part_kernel<<<256, 512, 0, stream>>>(QKb, Vtb, part0, part1, mlb);
    attn_merge_kernel<<<(M * Kd / 4) / 256, 256, 0, stream>>>(out, part0, part1, mlb);
}